// Round 7
// baseline (545.268 us; speedup 1.0000x reference)
//
#include <hip/hip_runtime.h>
#include <stdint.h>

#define B_TOT 65536

typedef __attribute__((ext_vector_type(8))) short s16x8;
typedef __attribute__((ext_vector_type(4))) float f32x4;
typedef unsigned short u16;
typedef unsigned int u32;
typedef unsigned long long u64;

// ---- workspace layout (u16 element offsets), weights in MFMA-fragment order:
//      frag(ct,kt) = [((ct*KT+kt)*64 + lane)*8 + j], n = ct*16+(lane&15), k = kt*32+(lane>>4)*8+j
#define OFF_SKIPW   0         // N=256 K=256 (16ct x 8kt)          65536
#define OFF_MD      65536     // 3 x (N=256 K=256)                 196608
#define OFF_GATEW   262144    // N=48 K=256 (3ct x 8kt)            12288
#define OFF_EXPW1   274432    // 13 x (N=128 K=256)                425984
#define OFF_EXPW2   700416    // 13 x (N=64 K=128)                 106496
#define OFF_DSKIPW  806912    // 6 x (N=64 K=256)                  98304
#define OFF_TOWW1   905216    // 6 x (N=64 K=64)                   24576
#define OFF_BVEC    929792    // 3 x 256 f32                       1536
#define OFF_PAR     931328    // 10240 u16 (bf16 back params)      10240
#define OFF_PARF    941568    // 1536 f32 front params             3072
#define OFF_EMB     944640    // [B/16][8 kt][64][8] bf16 frags = 16777216 u16
#define OFF_PERM    17852928  // B_TOT u32 = 131072 u16
#define OFF_CNT     17985024  // 8 u32 counters

// back param block layout (u16 element indices within the PAR block)
#define PAR_DSK  7488
#define PAR_TOW  8640
#define PAR_GB   10176
#define PAR_TB2  10224

__device__ __forceinline__ float bf2f(u16 h){ u32 v=((u32)h)<<16; return __builtin_bit_cast(float,v); }
__device__ __forceinline__ u16 f2bf(float f){
  u32 u=__builtin_bit_cast(u32,f);
  u += 0x7fffu + ((u>>16)&1u);
  return (u16)(u>>16);
}
__device__ __forceinline__ f32x4 mfma16(s16x8 a, s16x8 b, f32x4 c){
  return __builtin_amdgcn_mfma_f32_16x16x32_bf16(a,b,c,0,0,0);
}
__device__ __forceinline__ void lds_fence(){
  asm volatile("s_waitcnt lgkmcnt(0)" ::: "memory");
  __builtin_amdgcn_sched_barrier(0);   // rule #18: keep ops from hoisting past the wait
}

// async global->LDS staging: wave-striped 1KB units, LDS dest = uniform base + lane*16
__device__ __forceinline__ void gstage(const u16* gsrc, u16* ldsdst, int nbytes, int wv, int lane, int nw){
  for(int off = wv*1024; off < nbytes; off += nw*1024){
    __builtin_amdgcn_global_load_lds(
      (const __attribute__((address_space(1))) u32*)((const char*)gsrc + off + lane*16),
      (__attribute__((address_space(3))) u32*)((char*)ldsdst + off),
      16, 0, 0);
  }
}

template<int NT>
__device__ __forceinline__ void ln16(const f32x4* a, float invN, float* mu, float* rs){
  float s[4], q[4];
#pragma unroll
  for(int r=0;r<4;r++){ float aa=0.f,bb=0.f;
#pragma unroll
    for(int t=0;t<NT;t++){ float v=a[t][r]; aa+=v; bb+=v*v; }
    s[r]=aa; q[r]=bb; }
#pragma unroll
  for(int m=1;m<16;m<<=1){
#pragma unroll
    for(int r=0;r<4;r++){ s[r]+=__shfl_xor(s[r],m,16); q[r]+=__shfl_xor(q[r],m,16); } }
#pragma unroll
  for(int r=0;r<4;r++){ float m_=s[r]*invN; float v=q[r]*invN-m_*m_; mu[r]=m_; rs[r]=rsqrtf(v+1e-5f); }
}

// ============================ sort kernels (domain counting sort, UNPADDED) ====
__global__ __launch_bounds__(64) void k_sortinit(u16* __restrict__ ws){
  if(threadIdx.x<8) ((u32*)(ws+OFF_CNT))[threadIdx.x]=0u;
}
__global__ __launch_bounds__(256) void k_count(const int* __restrict__ x, u16* __restrict__ ws){
  u32* cnt=(u32*)(ws+OFF_CNT);
  int i=blockIdx.x*256+threadIdx.x;
  int lane=threadIdx.x&63;
  int d=x[15*B_TOT+i];
  u64 m0=__ballot(d==0), m1=__ballot(d==1), m2=__ballot(d==2);
  if(lane==0){
    if(m0) atomicAdd(&cnt[0],(u32)__popcll(m0));
    if(m1) atomicAdd(&cnt[1],(u32)__popcll(m1));
    if(m2) atomicAdd(&cnt[2],(u32)__popcll(m2));
  }
}
__global__ __launch_bounds__(256) void k_scatter(const int* __restrict__ x, u16* __restrict__ ws){
  u32* cnt=(u32*)(ws+OFF_CNT);
  u32* perm=(u32*)(ws+OFF_PERM);
  int i=blockIdx.x*256+threadIdx.x;
  int lane=threadIdx.x&63;
  int d=x[15*B_TOT+i];
  u32 c0=cnt[0], c1=cnt[1];
  u32 s1=c0, s2=c0+c1;                // NO padding: total positions = 65536 exactly
  u64 m0=__ballot(d==0), m1=__ballot(d==1), m2=__ballot(d==2);
  u32 b0v=0,b1v=0,b2v=0;
  if(lane==0){
    if(m0) b0v=atomicAdd(&cnt[3],(u32)__popcll(m0));
    if(m1) b1v=atomicAdd(&cnt[4],(u32)__popcll(m1));
    if(m2) b2v=atomicAdd(&cnt[5],(u32)__popcll(m2));
  }
  b0v=__shfl(b0v,0,64); b1v=__shfl(b1v,0,64); b2v=__shfl(b2v,0,64);
  u64 below=(1ull<<lane)-1ull;
  u32 pos;
  if(d==0)      pos=    b0v+(u32)__popcll(m0&below);
  else if(d==1) pos=s1+ b1v+(u32)__popcll(m1&below);
  else          pos=s2+ b2v+(u32)__popcll(m2&below);
  perm[pos]=(u32)i;
}

// ============================ pack kernel (weights -> frag layout) ============================
__global__ __launch_bounds__(256) void k_pack(
    const float* __restrict__ skip_W, const float* __restrict__ gate_W,
    const float* __restrict__ exp_W1, const float* __restrict__ dexp_W1, const float* __restrict__ texp_W1,
    const float* __restrict__ exp_W2, const float* __restrict__ dexp_W2, const float* __restrict__ texp_W2,
    const float* __restrict__ dskip_W, const float* __restrict__ tow_W1,
    u16* __restrict__ ws)
{
  int i=blockIdx.x*256+threadIdx.x;
  if(i>=OFF_BVEC) return;
  if(i>=OFF_MD && i<OFF_GATEW) return;   // Md done by k_fold
  float v;
  if(i<OFF_MD){
    int l=i; int j=l&7, lane=(l>>3)&63, kt=(l>>9)&7, ct=l>>12;
    int n=ct*16+(lane&15), k=kt*32+((lane>>4)<<3)+j;
    v = skip_W[k*256+n];
  } else if(i<OFF_EXPW1){
    int l=i-OFF_GATEW; int j=l&7, lane=(l>>3)&63, kt=(l>>9)&7, ct=l>>12;
    int n=ct*16+(lane&15), k=kt*32+((lane>>4)<<3)+j;
    int k6=n>>3, e=n&7;
    v = gate_W[(k6*256+k)*8+e];
  } else if(i<OFF_EXPW2){
    int l=i-OFF_EXPW1; int e=l>>15, r=l&32767;
    int j=r&7, lane=(r>>3)&63, kt=(r>>9)&7, ct=r>>12;
    int n=ct*16+(lane&15), k=kt*32+((lane>>4)<<3)+j;
    v = (e<8)? exp_W1[(e*256+k)*128+n] : (e<11)? dexp_W1[((e-8)*256+k)*128+n] : texp_W1[((e-11)*256+k)*128+n];
  } else if(i<OFF_DSKIPW){
    int l=i-OFF_EXPW1; // recomputed below
    l=i-OFF_EXPW2; int e=l>>13, r=l&8191;
    int j=r&7, lane=(r>>3)&63, kt=(r>>9)&3, ct=r>>11;
    int n=ct*16+(lane&15), k=kt*32+((lane>>4)<<3)+j;
    v = (e<8)? exp_W2[(e*128+k)*64+n] : (e<11)? dexp_W2[((e-8)*128+k)*64+n] : texp_W2[((e-11)*128+k)*64+n];
  } else if(i<OFF_TOWW1){
    int l=i-OFF_DSKIPW; int s=l>>14, r=l&16383;
    int j=r&7, lane=(r>>3)&63, kt=(r>>9)&7, ct=r>>12;
    int n=ct*16+(lane&15), k=kt*32+((lane>>4)<<3)+j;
    v = dskip_W[(s*256+k)*64+n];
  } else {
    int l=i-OFF_TOWW1; int s=l>>12, r=l&4095;
    int j=r&7, lane=(r>>3)&63, kt=(r>>9)&1, ct=r>>10;
    int n=ct*16+(lane&15), k=kt*32+((lane>>4)<<3)+j;
    v = tow_W1[(s*64+k)*64+n];
  }
  ws[i]=f2bf(v);
}

// ============================ param pack kernel ====
__global__ __launch_bounds__(256) void k_packpar(
    const float* __restrict__ exp_b1,const float* __restrict__ exp_g1,const float* __restrict__ exp_be1,
    const float* __restrict__ exp_b2,const float* __restrict__ exp_g2,const float* __restrict__ exp_be2,
    const float* __restrict__ dexp_b1,const float* __restrict__ dexp_g1,const float* __restrict__ dexp_be1,
    const float* __restrict__ dexp_b2,const float* __restrict__ dexp_g2,const float* __restrict__ dexp_be2,
    const float* __restrict__ texp_b1,const float* __restrict__ texp_g1,const float* __restrict__ texp_be1,
    const float* __restrict__ texp_b2,const float* __restrict__ texp_g2,const float* __restrict__ texp_be2,
    const float* __restrict__ dskip_b,const float* __restrict__ dskip_g,const float* __restrict__ dskip_be,
    const float* __restrict__ gate_b,
    const float* __restrict__ tow_b1,const float* __restrict__ tow_g,const float* __restrict__ tow_be,
    const float* __restrict__ tow_W2,const float* __restrict__ tow_b2,
    const float* __restrict__ skip_b,const float* __restrict__ skip_g,const float* __restrict__ skip_be,
    const float* __restrict__ star_b,const float* __restrict__ star_g,const float* __restrict__ star_be,
    u16* __restrict__ ws)
{
  int i=blockIdx.x*256+threadIdx.x;
  float* parf=(float*)(ws+OFF_PARF);
  if(i<10240){
    float v=0.f;
    if(i<PAR_DSK){
      int e=i/576, r=i%576;
      const float *b1,*g1,*be1,*b2,*g2,*be2;
      if(e<8){ b1=exp_b1+e*128; g1=exp_g1+e*128; be1=exp_be1+e*128;
               b2=exp_b2+e*64;  g2=exp_g2+e*64;  be2=exp_be2+e*64; }
      else if(e<11){ int q=e-8; b1=dexp_b1+q*128; g1=dexp_g1+q*128; be1=dexp_be1+q*128;
               b2=dexp_b2+q*64; g2=dexp_g2+q*64; be2=dexp_be2+q*64; }
      else { int q=e-11; b1=texp_b1+q*128; g1=texp_g1+q*128; be1=texp_be1+q*128;
               b2=texp_b2+q*64; g2=texp_g2+q*64; be2=texp_be2+q*64; }
      v = (r<128)? b1[r] : (r<256)? g1[r-128] : (r<384)? be1[r-256]
        : (r<448)? b2[r-384] : (r<512)? g2[r-448] : be2[r-512];
    } else if(i<PAR_TOW){
      int l=i-PAR_DSK; int j=l/192, r=l%192;
      v = (r<64)? dskip_b[j*64+r] : (r<128)? dskip_g[j*64+r-64] : dskip_be[j*64+r-128];
    } else if(i<PAR_GB){
      int l=i-PAR_TOW; int k6=l/256, r=l%256;
      v = (r<64)? tow_b1[k6*64+r] : (r<128)? tow_g[k6*64+r-64]
        : (r<192)? tow_be[k6*64+r-128] : tow_W2[k6*64+r-192];
    } else if(i<PAR_TB2){ v=gate_b[i-PAR_GB]; }
    else if(i<PAR_TB2+6){ v=tow_b2[i-PAR_TB2]; }
    ws[OFF_PAR+i]=f2bf(v);
  } else if(i<10240+1536){
    int l=i-10240;
    parf[l] = (l<256)? skip_b[l] : (l<512)? skip_g[l-256] : (l<768)? skip_be[l-512]
            : (l<1024)? star_b[l-768] : (l<1280)? star_g[l-1024] : star_be[l-1280];
  }
}

// ============================ fold kernel ====
__global__ __launch_bounds__(256) void k_fold(
    const float* __restrict__ slot_W, const float* __restrict__ shared_W, const float* __restrict__ star_W,
    const float* __restrict__ slot_b, const float* __restrict__ shared_b,
    u16* __restrict__ ws)
{
  __shared__ float w[512];
  int bid=blockIdx.x, tid=threadIdx.x;
  if(bid<768){
    int d=bid>>8, k=bid&255;
    for(int j=tid;j<512;j+=256) w[j]=slot_W[(d*256+k)*512+j]*shared_W[k*512+j];
    __syncthreads();
    int n=tid; float a=0.f;
    for(int j=0;j<512;j++) a += w[j]*star_W[j*256+n];
    int ct=n>>4, l15=n&15, kt=k>>5, hi=(k>>3)&3, j8=k&7;
    ws[OFF_MD + d*65536 + (((ct*8+kt)*64 + hi*16 + l15)<<3) + j8] = f2bf(a);
  } else {
    int d=bid-768;
    for(int j=tid;j<512;j+=256) w[j]=slot_b[d*512+j]+shared_b[j];
    __syncthreads();
    int n=tid; float a=0.f;
    for(int j=0;j<512;j++) a += w[j]*star_W[j*256+n];
    ((float*)(ws+OFF_BVEC))[d*256+n]=a;
  }
}

// ============================ front kernel (sorted rows, unpadded) ============================
// 256 threads / 128 sorted rows. Block domains = contiguous [dlo,dhi] (pure for all but <=2 blocks).
__global__ __launch_bounds__(256,2) void k_front(
    const int* __restrict__ x, const float* __restrict__ emb_tables,
    u16* __restrict__ wsu)
{
  __shared__ __align__(16) u16 shbuf[33792];   // trb[4][32][264] ; aliases Wbuf[2][8192]
  __shared__ float bvecL[768];
  __shared__ float parF[1536];

  const int tid=threadIdx.x, lane=tid&63, wv=tid>>6;
  const int l15=lane&15, hq=lane>>4;
  const int b0=blockIdx.x*128, rowbase=b0+wv*32;
  const f32x4 fz={0.f,0.f,0.f,0.f};
  const s16x8 zf={0,0,0,0,0,0,0,0};
  u16* Wb[2]={shbuf, shbuf+8192};
  u16* trbw = shbuf + wv*8448;   // [32][264]
  u16* embp = wsu+OFF_EMB;
  const u32* perm=(const u32*)(wsu+OFF_PERM);

  gstage(wsu+OFF_SKIPW, Wb[0], 16384, wv, lane, 4);
  gstage(wsu+OFF_BVEC, (u16*)bvecL, 3072, wv, lane, 4);
  gstage(wsu+OFF_PARF, (u16*)parF, 6144, wv, lane, 4);

  const int dlo=__builtin_amdgcn_readfirstlane(x[15*B_TOT+(int)perm[b0]]);
  const int dhi=__builtin_amdgcn_readfirstlane(x[15*B_TOT+(int)perm[b0+127]]);

  int dmA[2], dm[2][4];
  s16x8 af[2][8];
#pragma unroll
  for(int rt=0;rt<2;rt++){
    int prow=(int)perm[rowbase+rt*16+l15];
    dmA[rt]=x[15*B_TOT+prow];
#pragma unroll
    for(int r=0;r<4;r++) dm[rt][r]=x[15*B_TOT+(int)perm[rowbase+rt*16+hq*4+r]];
#pragma unroll
    for(int kt=0;kt<8;kt++){
      int f=kt*2+(hq>>1), j0=(hq&1)*8;
      int idx=x[f*B_TOT+prow];
      const float* sp=emb_tables + (size_t)(f*1000+idx)*16 + j0;
      float4 v0=*(const float4*)sp, v1=*(const float4*)(sp+4);
      union{ u16 h[8]; s16x8 v; } t;
      t.h[0]=f2bf(v0.x); t.h[1]=f2bf(v0.y); t.h[2]=f2bf(v0.z); t.h[3]=f2bf(v0.w);
      t.h[4]=f2bf(v1.x); t.h[5]=f2bf(v1.y); t.h[6]=f2bf(v1.z); t.h[7]=f2bf(v1.w);
      af[rt][kt]=t.v;
    }
  }
  __syncthreads();
  int cur=0;

  f32x4 acc[2][16];
#pragma unroll
  for(int rt=0;rt<2;rt++)
#pragma unroll
    for(int ct=0;ct<16;ct++) acc[rt][ct]=fz;

  // ---- skip MLP: 8 chunks ----
#pragma unroll
  for(int c=0;c<8;c++){
    if(c<7) gstage(wsu+OFF_SKIPW+(c+1)*8192, Wb[cur^1], 16384, wv, lane, 4);
    const u16* B=Wb[cur];
#pragma unroll
    for(int kt=0;kt<8;kt++){
#pragma unroll
      for(int i=0;i<2;i++){
        s16x8 bf=*(const s16x8*)(B + (((i*8+kt)*64+lane)<<3));
        acc[0][c*2+i]=mfma16(af[0][kt],bf,acc[0][c*2+i]);
        acc[1][c*2+i]=mfma16(af[1][kt],bf,acc[1][c*2+i]);
      }
    }
    __syncthreads(); cur^=1;
  }
  // skip epilogue -> trb
#pragma unroll
  for(int rt=0;rt<2;rt++){
#pragma unroll
    for(int ct=0;ct<16;ct++){ float bb=parF[ct*16+l15];
#pragma unroll
      for(int r=0;r<4;r++) acc[rt][ct][r]+=bb; }
    float mu[4],rs[4];
    ln16<16>(&acc[rt][0], 1.f/256.f, mu, rs);
#pragma unroll
    for(int ct=0;ct<16;ct++){
      int col=ct*16+l15;
      float gv=parF[256+col], bev=parF[512+col];
#pragma unroll
      for(int r=0;r<4;r++){
        float v=fmaxf((acc[rt][ct][r]-mu[r])*rs[r]*gv+bev,0.f);
        trbw[(rt*16+hq*4+r)*264 + col]=f2bf(v);
      }
    }
  }
  lds_fence();
  // store skip frags to global emb (read back at the end)
#pragma unroll
  for(int rt=0;rt<2;rt++){
    int rtg=(b0>>4)+wv*2+rt;
#pragma unroll
    for(int kt=0;kt<8;kt++){
      s16x8 v=*(const s16x8*)(trbw + (rt*16+l15)*264 + kt*32+hq*8);
      *(s16x8*)(embp + (((size_t)(rtg*8+kt)*64+lane)<<3)) = v;
    }
  }
  __syncthreads();                       // all trb reads done -> Wbuf reusable
  gstage(wsu+OFF_MD+dlo*65536, Wb[0], 16384, wv, lane, 4);
  __syncthreads();
  cur=0;

  // ---- star: sum over dd in [dlo,dhi] of mask_dd(row) @ Md[dd] ----
#pragma unroll
  for(int rt=0;rt<2;rt++)
#pragma unroll
    for(int ct=0;ct<16;ct++) acc[rt][ct]=fz;
  for(int dd=dlo;dd<=dhi;dd++){
#pragma unroll
    for(int c=0;c<8;c++){
      if(c<7)        gstage(wsu+OFF_MD+dd*65536+(c+1)*8192, Wb[cur^1], 16384, wv, lane, 4);
      else if(dd<dhi) gstage(wsu+OFF_MD+(dd+1)*65536,       Wb[cur^1], 16384, wv, lane, 4);
      const u16* B=Wb[cur];
#pragma unroll
      for(int kt=0;kt<8;kt++){
        s16x8 a0=(dmA[0]==dd)?af[0][kt]:zf;    // inline mask: no 64-reg hoist
        s16x8 a1=(dmA[1]==dd)?af[1][kt]:zf;
#pragma unroll
        for(int i=0;i<2;i++){
          s16x8 bf=*(const s16x8*)(B + (((i*8+kt)*64+lane)<<3));
          acc[0][c*2+i]=mfma16(a0,bf,acc[0][c*2+i]);
          acc[1][c*2+i]=mfma16(a1,bf,acc[1][c*2+i]);
        }
      }
      __syncthreads(); cur^=1;
    }
  }

  // star epilogue -> trb -> + skip frags (global) -> final emb frags
#pragma unroll
  for(int rt=0;rt<2;rt++){
#pragma unroll
    for(int ct=0;ct<16;ct++){
      int col=ct*16+l15; float sb=parF[768+col];
#pragma unroll
      for(int r=0;r<4;r++) acc[rt][ct][r] += sb + bvecL[dm[rt][r]*256+col];
    }
    float mu[4],rs[4];
    ln16<16>(&acc[rt][0], 1.f/256.f, mu, rs);
#pragma unroll
    for(int ct=0;ct<16;ct++){
      int col=ct*16+l15;
      float gv=parF[1024+col], bev=parF[1280+col];
#pragma unroll
      for(int r=0;r<4;r++){
        float v=fmaxf((acc[rt][ct][r]-mu[r])*rs[r]*gv+bev,0.f);
        trbw[(rt*16+hq*4+r)*264 + col]=f2bf(v);
      }
    }
  }
  lds_fence();
#pragma unroll
  for(int rt=0;rt<2;rt++){
    int rtg=(b0>>4)+wv*2+rt;
#pragma unroll
    for(int kt=0;kt<8;kt++){
      s16x8 vs=*(const s16x8*)(trbw + (rt*16+l15)*264 + kt*32+hq*8);
      s16x8 vk=*(const s16x8*)(embp + (((size_t)(rtg*8+kt)*64+lane)<<3));
      union{ u16 h[8]; s16x8 v; } t;
#pragma unroll
      for(int j=0;j<8;j++) t.h[j]=f2bf(bf2f((u16)vs[j])+bf2f((u16)vk[j]));
      *(s16x8*)(embp + (((size_t)(rtg*8+kt)*64+lane)<<3)) = t.v;
    }
  }
}

// ============================ k_B: BARRIER-FREE fused back half ====
// 256 thr / 4 waves / 128 sorted rows per block; each wave owns 32 rows and is fully
// independent: weight B-fragments stream straight from global (L2-hot, ~2MB total)
// into registers — no LDS weight ring, no s_barrier anywhere. Per-wave LDS only for
// the W1->W2 transpose (trb) and gate values (gateF), fenced with lgkmcnt(0).
__global__ __launch_bounds__(256,1) void k_B(
    const int* __restrict__ x, u16* __restrict__ wsu, float* __restrict__ out)
{
  __shared__ __align__(16) u16 trb[4][32][136];    // 34KB per-wave transpose (pitch 272B)
  __shared__ __align__(16) u32 gateF[4][32][8];    // 4KB per-wave (g_T0|g_T1) packed bf16

  const int tid=threadIdx.x, lane=tid&63, wv=tid>>6;
  const int l15=lane&15, hq=lane>>4;
  const int rowbase=blockIdx.x*128 + wv*32;
  const f32x4 fz={0.f,0.f,0.f,0.f};
  const u16* embp=wsu+OFF_EMB;
  const u16* parE=wsu+OFF_PAR;       // all back params: direct global (L2)
  const u32* perm=(const u32*)(wsu+OFF_PERM);
  u16* trbw=&trb[wv][0][0];

  // per-WAVE domain range (sorted rows): uniform for all but <=2 waves in the grid
  const int dlo=__builtin_amdgcn_readfirstlane(x[15*B_TOT+(int)perm[rowbase]]);
  const int dhi=__builtin_amdgcn_readfirstlane(x[15*B_TOT+(int)perm[rowbase+31]]);
  const int ndom=dhi-dlo+1;
  const int NU=10+ndom;

  u32 pv[2][4]; int dm[2][4];
#pragma unroll
  for(int rt=0;rt<2;rt++)
#pragma unroll
    for(int r=0;r<4;r++){
      u32 pp=perm[rowbase + rt*16 + hq*4 + r];
      pv[rt][r]=pp;
      dm[rt][r]=x[15*B_TOT+(int)pp];
    }

  s16x8 af[2][8];
#pragma unroll
  for(int rt=0;rt<2;rt++){
    int rtg=(rowbase>>4)+rt;
#pragma unroll
    for(int kt=0;kt<8;kt++)
      af[rt][kt]=*(const s16x8*)(embp + (((size_t)(rtg*8+kt)*64+lane)<<3));
  }

  f32x4 fa0[2][4], fa1[2][4];   // fused accumulators, C-frag layout, T=0 / T=1
#pragma unroll
  for(int rt=0;rt<2;rt++)
#pragma unroll
    for(int ct=0;ct<4;ct++){ fa0[rt][ct]=fz; fa1[rt][ct]=fz; }

  // ---- gates: weights direct from global ----
  {
    f32x4 gacc[2][3];
#pragma unroll
    for(int rt=0;rt<2;rt++)
#pragma unroll
      for(int ct=0;ct<3;ct++) gacc[rt][ct]=fz;
    const u16* GW=wsu+OFF_GATEW;
#pragma unroll
    for(int kt=0;kt<8;kt++){
      s16x8 wf[3];
#pragma unroll
      for(int ct=0;ct<3;ct++) wf[ct]=*(const s16x8*)(GW + (((ct*8+kt)*64+lane)<<3));
#pragma unroll
      for(int ct=0;ct<3;ct++){
        gacc[0][ct]=mfma16(af[0][kt],wf[ct],gacc[0][ct]);
        gacc[1][ct]=mfma16(af[1][kt],wf[ct],gacc[1][ct]);
      }
    }
    u16* gFh=(u16*)&gateF[wv][0][0];
#pragma unroll
    for(int rt=0;rt<2;rt++)
#pragma unroll
      for(int ct=0;ct<3;ct++){
        int k6=ct*2+(l15>>3), e=l15&7;
        float gb=bf2f(parE[PAR_GB + k6*8+e]);
#pragma unroll
        for(int r=0;r<4;r++){
          float v=gacc[rt][ct][r]+gb;
          float mx=v;
          mx=fmaxf(mx,__shfl_xor(mx,1,8)); mx=fmaxf(mx,__shfl_xor(mx,2,8)); mx=fmaxf(mx,__shfl_xor(mx,4,8));
          float pe=__expf(v-mx);
          float ss=pe;
          ss+=__shfl_xor(ss,1,8); ss+=__shfl_xor(ss,2,8); ss+=__shfl_xor(ss,4,8);
          int brow=rt*16+hq*4+r;
          int dmv=dm[rt][r];
          if(k6==dmv)   gFh[(brow*8+e)*2]  =f2bf(pe/ss);
          if(k6==3+dmv) gFh[(brow*8+e)*2+1]=f2bf(pe/ss);
        }
      }
    lds_fence();
  }

  // ---- NU two-layer units: exp0..7, dexp[dlo..dhi], texp0, texp1 ----
  for(int ui=0;ui<NU;ui++){
    const int u = (ui<8)? ui : (ui<8+ndom)? (8+dlo+(ui-8)) : (11+(ui-8-ndom));
    const u16* W1=wsu+OFF_EXPW1+(size_t)u*32768;
    const u16* W2=wsu+OFF_EXPW2+(size_t)u*8192;
    const u16* pe_=parE + u*576;
    f32x4 acc1[2][8];
#pragma unroll
    for(int rt=0;rt<2;rt++)
#pragma unroll
      for(int ct=0;ct<8;ct++) acc1[rt][ct]=fz;
#pragma unroll
    for(int kt=0;kt<8;kt++){
      s16x8 wf[8];
#pragma unroll
      for(int ct=0;ct<8;ct++) wf[ct]=*(const s16x8*)(W1 + (((ct*8+kt)*64+lane)<<3));
#pragma unroll
      for(int ct=0;ct<8;ct++){
        acc1[0][ct]=mfma16(af[0][kt],wf[ct],acc1[0][ct]);
        acc1[1][ct]=mfma16(af[1][kt],wf[ct],acc1[1][ct]);
      }
    }
    // layer-1 epilogue -> trb (per-wave)
#pragma unroll
    for(int rt=0;rt<2;rt++){
#pragma unroll
      for(int ct=0;ct<8;ct++){ float bb=bf2f(pe_[ct*16+l15]);
#pragma unroll
        for(int r=0;r<4;r++) acc1[rt][ct][r]+=bb; }
      float mu[4],rs[4],nm[4];
      ln16<8>(&acc1[rt][0],1.f/128.f,mu,rs);
#pragma unroll
      for(int r=0;r<4;r++) nm[r]=-mu[r]*rs[r];
#pragma unroll
      for(int ct=0;ct<8;ct++){
        int col=ct*16+l15;
        float gv=bf2f(pe_[128+col]), bev=bf2f(pe_[256+col]);
#pragma unroll
        for(int r=0;r<4;r++){
          float vn=fmaf(acc1[rt][ct][r],rs[r],nm[r]);
          trbw[(rt*16+hq*4+r)*136+col]=f2bf(fmaxf(fmaf(vn,gv,bev),0.f));
        }
      }
    }
    lds_fence();
    s16x8 af2[2][4];
#pragma unroll
    for(int rt=0;rt<2;rt++)
#pragma unroll
      for(int kt=0;kt<4;kt++)
        af2[rt][kt]=*(const s16x8*)(trbw+(rt*16+l15)*136+kt*32+hq*8);
    lds_fence();
    f32x4 acc2[2][4];
#pragma unroll
    for(int rt=0;rt<2;rt++)
#pragma unroll
      for(int ct=0;ct<4;ct++) acc2[rt][ct]=fz;
#pragma unroll
    for(int kt=0;kt<4;kt++){
      s16x8 wf[4];
#pragma unroll
      for(int ct=0;ct<4;ct++) wf[ct]=*(const s16x8*)(W2 + (((ct*4+kt)*64+lane)<<3));
#pragma unroll
      for(int ct=0;ct<4;ct++){
        acc2[0][ct]=mfma16(af2[0][kt],wf[ct],acc2[0][ct]);
        acc2[1][ct]=mfma16(af2[1][kt],wf[ct],acc2[1][ct]);
      }
    }
    // layer-2 epilogue + gated fusion (per-row weights): stays in registers
#pragma unroll
    for(int rt=0;rt<2;rt++){
#pragma unroll
      for(int ct=0;ct<4;ct++){ float bb=bf2f(pe_[384+ct*16+l15]);
#pragma unroll
        for(int r=0;r<4;r++) acc2[rt][ct][r]+=bb; }
      float mu[4],rs[4],nm[4];
      ln16<4>(&acc2[rt][0],1.f/64.f,mu,rs);
#pragma unroll
      for(int r=0;r<4;r++) nm[r]=-mu[r]*rs[r];
      float g0v[4],g1v[4];
      if(ui<8){
#pragma unroll
        for(int r=0;r<4;r++){ u32 gg=gateF[wv][rt*16+hq*4+r][ui];
          g0v[r]=bf2f((u16)(gg&0xffffu)); g1v[r]=bf2f((u16)(gg>>16)); }
      } else if(ui<8+ndom){
        int du=dlo+(ui-8);
#pragma unroll
        for(int r=0;r<4;r++){ float m=(dm[rt][r]==du)?1.f:0.f; g0v[r]=m; g1v[r]=m; }
      } else {
        int q=ui-8-ndom;
#pragma unroll
        for(int r=0;r<4;r++){
          g0v[r]=((dm[rt][r]&1)==q)?1.f:0.f;
          g1v[r]=(((dm[rt][r]+1)&1)==q)?1.f:0.f;
        }
      }
#pragma unroll
      for(int ct=0;ct<4;ct++){
        int col=ct*16+l15;
        float gv=bf2f(pe_[448+col]), bev=bf2f(pe_[512+col]);
#pragma unroll
        for(int r=0;r<4;r++){
          float vn=fmaf(acc2[rt][ct][r],rs[r],nm[r]);
          float o=fmaxf(fmaf(vn,gv,bev),0.f);
          fa0[rt][ct][r]=fmaf(g0v[r],o,fa0[rt][ct][r]);
          fa1[rt][ct][r]=fmaf(g1v[r],o,fa1[rt][ct][r]);
        }
      }
    }
  }

  // ---- dskip units: per domain dd: j=dd (->fa0), j=3+dd (->fa1), weight 0.5, per-row mask ----
  for(int dq=0;dq<2*ndom;dq++){
    const int dd=dlo+(dq>>1);
    const int jj=(dq&1)? (3+dd) : dd;
    const u16* WD=wsu+OFF_DSKIPW+(size_t)jj*16384;
    f32x4 a3[2][4];
#pragma unroll
    for(int rt=0;rt<2;rt++)
#pragma unroll
      for(int ct=0;ct<4;ct++) a3[rt][ct]=fz;
#pragma unroll
    for(int kt=0;kt<8;kt++){
      s16x8 wf[4];
#pragma unroll
      for(int ct=0;ct<4;ct++) wf[ct]=*(const s16x8*)(WD + (((ct*8+kt)*64+lane)<<3));
#pragma unroll
      for(int ct=0;ct<4;ct++){
        a3[0][ct]=mfma16(af[0][kt],wf[ct],a3[0][ct]);
        a3[1][ct]=mfma16(af[1][kt],wf[ct],a3[1][ct]);
      }
    }
    const int pb=PAR_DSK+jj*192;
#pragma unroll
    for(int rt=0;rt<2;rt++){
#pragma unroll
      for(int ct=0;ct<4;ct++){ float bb=bf2f(parE[pb+ct*16+l15]);
#pragma unroll
        for(int r=0;r<4;r++) a3[rt][ct][r]+=bb; }
      float mu[4],rs[4],nm[4],mk[4];
      ln16<4>(&a3[rt][0],1.f/64.f,mu,rs);
#pragma unroll
      for(int r=0;r<4;r++){ nm[r]=-mu[r]*rs[r]; mk[r]=(dm[rt][r]==dd)?0.5f:0.f; }
#pragma unroll
      for(int ct=0;ct<4;ct++){
        int col=ct*16+l15;
        float gv=bf2f(parE[pb+64+col]), bev=bf2f(parE[pb+128+col]);
#pragma unroll
        for(int r=0;r<4;r++){
          float vn=fmaf(a3[rt][ct][r],rs[r],nm[r]);
          float o=fmaxf(fmaf(vn,gv,bev),0.f);
          if((dq&1)==0) fa0[rt][ct][r]=fmaf(mk[r],o,fa0[rt][ct][r]);
          else          fa1[rt][ct][r]=fmaf(mk[r],o,fa1[rt][ct][r]);
        }
      }
    }
  }

  // ---- transpose fused accumulators to A-frags (T=0 cols 0..63, T=1 cols 64..127) ----
#pragma unroll
  for(int rt=0;rt<2;rt++)
#pragma unroll
    for(int ct=0;ct<4;ct++)
#pragma unroll
      for(int r=0;r<4;r++){
        int rr=(rt*16+hq*4+r)*136 + ct*16+l15;
        trbw[rr]   =f2bf(fa0[rt][ct][r]);
        trbw[rr+64]=f2bf(fa1[rt][ct][r]);
      }
  lds_fence();
  s16x8 aft0[2][2], aft1[2][2];
#pragma unroll
  for(int rt=0;rt<2;rt++)
#pragma unroll
    for(int kt=0;kt<2;kt++){
      aft0[rt][kt]=*(const s16x8*)(trbw+(rt*16+l15)*136+kt*32+hq*8);
      aft1[rt][kt]=*(const s16x8*)(trbw+(rt*16+l15)*136+64+kt*32+hq*8);
    }
  lds_fence();

  // ---- towers: per domain dd (k6=dd from aft0, k6=3+dd from aft1) ----
  for(int t=0;t<ndom;t++){
    const int dd=dlo+t;
#pragma unroll
    for(int s=0;s<2;s++){
      const int k6 = s? (3+dd) : dd;
      const u16* WT=wsu+OFF_TOWW1+(size_t)k6*4096;
      f32x4 ta[2][4];
#pragma unroll
      for(int rt=0;rt<2;rt++)
#pragma unroll
        for(int ct=0;ct<4;ct++) ta[rt][ct]=fz;
#pragma unroll
      for(int kt=0;kt<2;kt++){
        s16x8 wf[4];
#pragma unroll
        for(int ct=0;ct<4;ct++) wf[ct]=*(const s16x8*)(WT + (((ct*2+kt)*64+lane)<<3));
#pragma unroll
        for(int ct=0;ct<4;ct++){
          if(s==0){ ta[0][ct]=mfma16(aft0[0][kt],wf[ct],ta[0][ct]); ta[1][ct]=mfma16(aft0[1][kt],wf[ct],ta[1][ct]); }
          else    { ta[0][ct]=mfma16(aft1[0][kt],wf[ct],ta[0][ct]); ta[1][ct]=mfma16(aft1[1][kt],wf[ct],ta[1][ct]); }
        }
      }
      const int pb=PAR_TOW+k6*256;
#pragma unroll
      for(int rt=0;rt<2;rt++){
#pragma unroll
        for(int ct=0;ct<4;ct++){ float bb=bf2f(parE[pb+ct*16+l15]);
#pragma unroll
          for(int r=0;r<4;r++) ta[rt][ct][r]+=bb; }
        float mu[4],rs[4],nm[4];
        ln16<4>(&ta[rt][0],1.f/64.f,mu,rs);
#pragma unroll
        for(int r=0;r<4;r++) nm[r]=-mu[r]*rs[r];
        float pr[4]={0.f,0.f,0.f,0.f};
#pragma unroll
        for(int ct=0;ct<4;ct++){
          int col=ct*16+l15;
          float gv=bf2f(parE[pb+64+col]), bev=bf2f(parE[pb+128+col]), w2=bf2f(parE[pb+192+col]);
#pragma unroll
          for(int r=0;r<4;r++){
            float vn=fmaf(ta[rt][ct][r],rs[r],nm[r]);
            float o=fmaxf(fmaf(vn,gv,bev),0.f);
            pr[r]=fmaf(o,w2,pr[r]);
          }
        }
#pragma unroll
        for(int m=1;m<16;m<<=1){
#pragma unroll
          for(int r=0;r<4;r++) pr[r]+=__shfl_xor(pr[r],m,16);
        }
        if(l15==0){
          float tb2=bf2f(parE[PAR_TB2+k6]);
#pragma unroll
          for(int r=0;r<4;r++){
            if(dm[rt][r]==dd){
              float sv=pr[r]+tb2;
              out[(size_t)pv[rt][r]*2 + s] = 1.f/(1.f+__expf(-sv));
            }
          }
        }
      }
    }
  }
}

// ============================ launcher ============================
extern "C" void kernel_launch(void* const* d_in, const int* in_sizes, int n_in,
                              void* d_out, int out_size, void* d_ws, size_t ws_size,
                              hipStream_t stream)
{
  if(ws_size < (size_t)(OFF_CNT+32)*2) return;

  const int*   x          =(const int*)  d_in[0];
  const float* emb_tables =(const float*)d_in[1];
  const float* skip_W     =(const float*)d_in[2];
  const float* skip_b     =(const float*)d_in[3];
  const float* skip_g     =(const float*)d_in[4];
  const float* skip_be    =(const float*)d_in[5];
  const float* shared_W   =(const float*)d_in[6];
  const float* shared_b   =(const float*)d_in[7];
  const float* slot_W     =(const float*)d_in[8];
  const float* slot_b     =(const float*)d_in[9];
  const float* star_W     =(const float*)d_in[10];
  const float* star_b     =(const float*)d_in[11];
  const float* star_g     =(const float*)d_in[12];
  const float* star_be    =(const float*)d_in[13];
  const float* dskip_W    =(const float*)d_in[14];
  const float* dskip_b    =(const float*)d_in[15];
  const float* dskip_g    =(const float*)d_in[16];
  const float* dskip_be   =(const float*)d_in[17];
  const float* exp_W1     =(const float*)d_in[18];
  const float* exp_b1     =(const float*)d_in[19];
  const float* exp_g1     =(const float*)d_in[20];
  const float* exp_be1    =(const float*)d_in[21];
  const float* exp_W2     =(const float*)d_in[22];
  const float* exp_b2     =(const float*)d_in[23];
  const float* exp_g2     =(const float*)d_in[24];
  const float* exp_be2    =(const float*)d_in[25];
  const float* dexp_W1    =(const float*)d_in[26];
  const float* dexp_b1    =(const float*)d_in[27];
  const float* dexp_g1    =(const float*)d_in[28];
  const float* dexp_be1   =(const float*)d_in[29];
  const float* dexp_W2    =(const float*)d_in[30];
  const float* dexp_b2    =(const float*)d_in[31];
  const float* dexp_g2    =(const float*)d_in[32];
  const float* dexp_be2   =(const float*)d_in[33];
  const float* texp_W1    =(const float*)d_in[34];
  const float* texp_b1    =(const float*)d_in[35];
  const float* texp_g1    =(const float*)d_in[36];
  const float* texp_be1   =(const float*)d_in[37];
  const float* texp_W2    =(const float*)d_in[38];
  const float* texp_b2    =(const float*)d_in[39];
  const float* texp_g2    =(const float*)d_in[40];
  const float* texp_be2   =(const float*)d_in[41];
  const float* gate_W     =(const float*)d_in[42];
  const float* gate_b     =(const float*)d_in[43];
  const float* tow_W1     =(const float*)d_in[44];
  const float* tow_b1     =(const float*)d_in[45];
  const float* tow_g      =(const float*)d_in[46];
  const float* tow_be     =(const float*)d_in[47];
  const float* tow_W2     =(const float*)d_in[48];
  const float* tow_b2     =(const float*)d_in[49];

  u16* wsu=(u16*)d_ws;
  float* out=(float*)d_out;

  k_sortinit<<<1,64,0,stream>>>(wsu);
  k_count<<<B_TOT/256,256,0,stream>>>(x,wsu);
  k_scatter<<<B_TOT/256,256,0,stream>>>(x,wsu);
  k_pack<<<(OFF_BVEC+255)/256,256,0,stream>>>(skip_W,gate_W,
      exp_W1,dexp_W1,texp_W1,exp_W2,dexp_W2,texp_W2,dskip_W,tow_W1,wsu);
  k_packpar<<<46,256,0,stream>>>(
      exp_b1,exp_g1,exp_be1,exp_b2,exp_g2,exp_be2,
      dexp_b1,dexp_g1,dexp_be1,dexp_b2,dexp_g2,dexp_be2,
      texp_b1,texp_g1,texp_be1,texp_b2,texp_g2,texp_be2,
      dskip_b,dskip_g,dskip_be,gate_b,
      tow_b1,tow_g,tow_be,tow_W2,tow_b2,
      skip_b,skip_g,skip_be,star_b,star_g,star_be,wsu);
  k_fold<<<771,256,0,stream>>>(slot_W,shared_W,star_W,slot_b,shared_b,wsu);
  k_front<<<B_TOT/128,256,0,stream>>>(x,emb_tables,wsu);
  k_B<<<B_TOT/128,256,0,stream>>>(x,wsu,out);
}

// Round 8
// 396.033 us; speedup vs baseline: 1.3768x; 1.3768x over previous
//
#include <hip/hip_runtime.h>
#include <stdint.h>

#define B_TOT 65536

typedef __attribute__((ext_vector_type(8))) short s16x8;
typedef __attribute__((ext_vector_type(4))) float f32x4;
typedef unsigned short u16;
typedef unsigned int u32;
typedef unsigned long long u64;

// ---- workspace layout (u16 element offsets), weights in MFMA-fragment order:
//      frag(ct,kt) = [((ct*KT+kt)*64 + lane)*8 + j], n = ct*16+(lane&15), k = kt*32+(lane>>4)*8+j
#define OFF_SKIPW   0         // N=256 K=256 (16ct x 8kt)          65536
#define OFF_MD      65536     // 3 x (N=256 K=256)                 196608
#define OFF_GATEW   262144    // N=48 K=256 (3ct x 8kt)            12288
#define OFF_EXPW1   274432    // 13 x (N=128 K=256)                425984
#define OFF_EXPW2   700416    // 13 x (N=64 K=128)                 106496
#define OFF_DSKIPW  806912    // 6 x (N=64 K=256)                  98304
#define OFF_TOWW1   905216    // 6 x (N=64 K=64)                   24576
#define OFF_BVEC    929792    // 3 x 256 f32                       1536
#define OFF_PAR     931328    // 10240 u16 (bf16 back params)      10240
#define OFF_PARF    941568    // 1536 f32 front params             3072
#define OFF_EMB     944640    // [B/16][8 kt][64][8] bf16 frags = 16777216 u16
#define OFF_PERM    17852928  // B_TOT u32 = 131072 u16
#define OFF_CNT     17985024  // 8 u32 counters

// back param block layout (u16 element indices within the PAR block)
#define PAR_DSK  7488
#define PAR_TOW  8640
#define PAR_GB   10176
#define PAR_TB2  10224

__device__ __forceinline__ float bf2f(u16 h){ u32 v=((u32)h)<<16; return __builtin_bit_cast(float,v); }
__device__ __forceinline__ u16 f2bf(float f){
  u32 u=__builtin_bit_cast(u32,f);
  u += 0x7fffu + ((u>>16)&1u);
  return (u16)(u>>16);
}
__device__ __forceinline__ f32x4 mfma16(s16x8 a, s16x8 b, f32x4 c){
  return __builtin_amdgcn_mfma_f32_16x16x32_bf16(a,b,c,0,0,0);
}
__device__ __forceinline__ void lds_fence(){
  asm volatile("s_waitcnt lgkmcnt(0)" ::: "memory");
  __builtin_amdgcn_sched_barrier(0);   // rule #18: keep ops from hoisting past the wait
}

// async global->LDS staging: wave-striped 1KB units, LDS dest = uniform base + lane*16
__device__ __forceinline__ void gstage(const u16* gsrc, u16* ldsdst, int nbytes, int wv, int lane, int nw){
  for(int off = wv*1024; off < nbytes; off += nw*1024){
    __builtin_amdgcn_global_load_lds(
      (const __attribute__((address_space(1))) u32*)((const char*)gsrc + off + lane*16),
      (__attribute__((address_space(3))) u32*)((char*)ldsdst + off),
      16, 0, 0);
  }
}

template<int NT>
__device__ __forceinline__ void ln16(const f32x4* a, float invN, float* mu, float* rs){
  float s[4], q[4];
#pragma unroll
  for(int r=0;r<4;r++){ float aa=0.f,bb=0.f;
#pragma unroll
    for(int t=0;t<NT;t++){ float v=a[t][r]; aa+=v; bb+=v*v; }
    s[r]=aa; q[r]=bb; }
#pragma unroll
  for(int m=1;m<16;m<<=1){
#pragma unroll
    for(int r=0;r<4;r++){ s[r]+=__shfl_xor(s[r],m,16); q[r]+=__shfl_xor(q[r],m,16); } }
#pragma unroll
  for(int r=0;r<4;r++){ float m_=s[r]*invN; float v=q[r]*invN-m_*m_; mu[r]=m_; rs[r]=rsqrtf(v+1e-5f); }
}

// ============================ sort kernels (domain counting sort, UNPADDED) ====
__global__ __launch_bounds__(64) void k_sortinit(u16* __restrict__ ws){
  if(threadIdx.x<8) ((u32*)(ws+OFF_CNT))[threadIdx.x]=0u;
}
__global__ __launch_bounds__(256) void k_count(const int* __restrict__ x, u16* __restrict__ ws){
  u32* cnt=(u32*)(ws+OFF_CNT);
  int i=blockIdx.x*256+threadIdx.x;
  int lane=threadIdx.x&63;
  int d=x[15*B_TOT+i];
  u64 m0=__ballot(d==0), m1=__ballot(d==1), m2=__ballot(d==2);
  if(lane==0){
    if(m0) atomicAdd(&cnt[0],(u32)__popcll(m0));
    if(m1) atomicAdd(&cnt[1],(u32)__popcll(m1));
    if(m2) atomicAdd(&cnt[2],(u32)__popcll(m2));
  }
}
__global__ __launch_bounds__(256) void k_scatter(const int* __restrict__ x, u16* __restrict__ ws){
  u32* cnt=(u32*)(ws+OFF_CNT);
  u32* perm=(u32*)(ws+OFF_PERM);
  int i=blockIdx.x*256+threadIdx.x;
  int lane=threadIdx.x&63;
  int d=x[15*B_TOT+i];
  u32 c0=cnt[0], c1=cnt[1];
  u32 s1=c0, s2=c0+c1;                // NO padding: total positions = 65536 exactly
  u64 m0=__ballot(d==0), m1=__ballot(d==1), m2=__ballot(d==2);
  u32 b0v=0,b1v=0,b2v=0;
  if(lane==0){
    if(m0) b0v=atomicAdd(&cnt[3],(u32)__popcll(m0));
    if(m1) b1v=atomicAdd(&cnt[4],(u32)__popcll(m1));
    if(m2) b2v=atomicAdd(&cnt[5],(u32)__popcll(m2));
  }
  b0v=__shfl(b0v,0,64); b1v=__shfl(b1v,0,64); b2v=__shfl(b2v,0,64);
  u64 below=(1ull<<lane)-1ull;
  u32 pos;
  if(d==0)      pos=    b0v+(u32)__popcll(m0&below);
  else if(d==1) pos=s1+ b1v+(u32)__popcll(m1&below);
  else          pos=s2+ b2v+(u32)__popcll(m2&below);
  perm[pos]=(u32)i;
}

// ============================ pack kernel (weights -> frag layout) ============================
__global__ __launch_bounds__(256) void k_pack(
    const float* __restrict__ skip_W, const float* __restrict__ gate_W,
    const float* __restrict__ exp_W1, const float* __restrict__ dexp_W1, const float* __restrict__ texp_W1,
    const float* __restrict__ exp_W2, const float* __restrict__ dexp_W2, const float* __restrict__ texp_W2,
    const float* __restrict__ dskip_W, const float* __restrict__ tow_W1,
    u16* __restrict__ ws)
{
  int i=blockIdx.x*256+threadIdx.x;
  if(i>=OFF_BVEC) return;
  if(i>=OFF_MD && i<OFF_GATEW) return;   // Md done by k_fold
  float v;
  if(i<OFF_MD){
    int l=i; int j=l&7, lane=(l>>3)&63, kt=(l>>9)&7, ct=l>>12;
    int n=ct*16+(lane&15), k=kt*32+((lane>>4)<<3)+j;
    v = skip_W[k*256+n];
  } else if(i<OFF_EXPW1){
    int l=i-OFF_GATEW; int j=l&7, lane=(l>>3)&63, kt=(l>>9)&7, ct=l>>12;
    int n=ct*16+(lane&15), k=kt*32+((lane>>4)<<3)+j;
    int k6=n>>3, e=n&7;
    v = gate_W[(k6*256+k)*8+e];
  } else if(i<OFF_EXPW2){
    int l=i-OFF_EXPW1; int e=l>>15, r=l&32767;
    int j=r&7, lane=(r>>3)&63, kt=(r>>9)&7, ct=r>>12;
    int n=ct*16+(lane&15), k=kt*32+((lane>>4)<<3)+j;
    v = (e<8)? exp_W1[(e*256+k)*128+n] : (e<11)? dexp_W1[((e-8)*256+k)*128+n] : texp_W1[((e-11)*256+k)*128+n];
  } else if(i<OFF_DSKIPW){
    int l=i-OFF_EXPW2; int e=l>>13, r=l&8191;
    int j=r&7, lane=(r>>3)&63, kt=(r>>9)&3, ct=r>>11;
    int n=ct*16+(lane&15), k=kt*32+((lane>>4)<<3)+j;
    v = (e<8)? exp_W2[(e*128+k)*64+n] : (e<11)? dexp_W2[((e-8)*128+k)*64+n] : texp_W2[((e-11)*128+k)*64+n];
  } else if(i<OFF_TOWW1){
    int l=i-OFF_DSKIPW; int s=l>>14, r=l&16383;
    int j=r&7, lane=(r>>3)&63, kt=(r>>9)&7, ct=r>>12;
    int n=ct*16+(lane&15), k=kt*32+((lane>>4)<<3)+j;
    v = dskip_W[(s*256+k)*64+n];
  } else {
    int l=i-OFF_TOWW1; int s=l>>12, r=l&4095;
    int j=r&7, lane=(r>>3)&63, kt=(r>>9)&1, ct=r>>10;
    int n=ct*16+(lane&15), k=kt*32+((lane>>4)<<3)+j;
    v = tow_W1[(s*64+k)*64+n];
  }
  ws[i]=f2bf(v);
}

// ============================ param pack kernel ====
__global__ __launch_bounds__(256) void k_packpar(
    const float* __restrict__ exp_b1,const float* __restrict__ exp_g1,const float* __restrict__ exp_be1,
    const float* __restrict__ exp_b2,const float* __restrict__ exp_g2,const float* __restrict__ exp_be2,
    const float* __restrict__ dexp_b1,const float* __restrict__ dexp_g1,const float* __restrict__ dexp_be1,
    const float* __restrict__ dexp_b2,const float* __restrict__ dexp_g2,const float* __restrict__ dexp_be2,
    const float* __restrict__ texp_b1,const float* __restrict__ texp_g1,const float* __restrict__ texp_be1,
    const float* __restrict__ texp_b2,const float* __restrict__ texp_g2,const float* __restrict__ texp_be2,
    const float* __restrict__ dskip_b,const float* __restrict__ dskip_g,const float* __restrict__ dskip_be,
    const float* __restrict__ gate_b,
    const float* __restrict__ tow_b1,const float* __restrict__ tow_g,const float* __restrict__ tow_be,
    const float* __restrict__ tow_W2,const float* __restrict__ tow_b2,
    const float* __restrict__ skip_b,const float* __restrict__ skip_g,const float* __restrict__ skip_be,
    const float* __restrict__ star_b,const float* __restrict__ star_g,const float* __restrict__ star_be,
    u16* __restrict__ ws)
{
  int i=blockIdx.x*256+threadIdx.x;
  float* parf=(float*)(ws+OFF_PARF);
  if(i<10240){
    float v=0.f;
    if(i<PAR_DSK){
      int e=i/576, r=i%576;
      const float *b1,*g1,*be1,*b2,*g2,*be2;
      if(e<8){ b1=exp_b1+e*128; g1=exp_g1+e*128; be1=exp_be1+e*128;
               b2=exp_b2+e*64;  g2=exp_g2+e*64;  be2=exp_be2+e*64; }
      else if(e<11){ int q=e-8; b1=dexp_b1+q*128; g1=dexp_g1+q*128; be1=dexp_be1+q*128;
               b2=dexp_b2+q*64; g2=dexp_g2+q*64; be2=dexp_be2+q*64; }
      else { int q=e-11; b1=texp_b1+q*128; g1=texp_g1+q*128; be1=texp_be1+q*128;
               b2=texp_b2+q*64; g2=texp_g2+q*64; be2=texp_be2+q*64; }
      v = (r<128)? b1[r] : (r<256)? g1[r-128] : (r<384)? be1[r-256]
        : (r<448)? b2[r-384] : (r<512)? g2[r-448] : be2[r-512];
    } else if(i<PAR_TOW){
      int l=i-PAR_DSK; int j=l/192, r=l%192;
      v = (r<64)? dskip_b[j*64+r] : (r<128)? dskip_g[j*64+r-64] : dskip_be[j*64+r-128];
    } else if(i<PAR_GB){
      int l=i-PAR_TOW; int k6=l/256, r=l%256;
      v = (r<64)? tow_b1[k6*64+r] : (r<128)? tow_g[k6*64+r-64]
        : (r<192)? tow_be[k6*64+r-128] : tow_W2[k6*64+r-192];
    } else if(i<PAR_TB2){ v=gate_b[i-PAR_GB]; }
    else if(i<PAR_TB2+6){ v=tow_b2[i-PAR_TB2]; }
    ws[OFF_PAR+i]=f2bf(v);
  } else if(i<10240+1536){
    int l=i-10240;
    parf[l] = (l<256)? skip_b[l] : (l<512)? skip_g[l-256] : (l<768)? skip_be[l-512]
            : (l<1024)? star_b[l-768] : (l<1280)? star_g[l-1024] : star_be[l-1280];
  }
}

// ============================ fold kernel ====
__global__ __launch_bounds__(256) void k_fold(
    const float* __restrict__ slot_W, const float* __restrict__ shared_W, const float* __restrict__ star_W,
    const float* __restrict__ slot_b, const float* __restrict__ shared_b,
    u16* __restrict__ ws)
{
  __shared__ float w[512];
  int bid=blockIdx.x, tid=threadIdx.x;
  if(bid<768){
    int d=bid>>8, k=bid&255;
    for(int j=tid;j<512;j+=256) w[j]=slot_W[(d*256+k)*512+j]*shared_W[k*512+j];
    __syncthreads();
    int n=tid; float a=0.f;
    for(int j=0;j<512;j++) a += w[j]*star_W[j*256+n];
    int ct=n>>4, l15=n&15, kt=k>>5, hi=(k>>3)&3, j8=k&7;
    ws[OFF_MD + d*65536 + (((ct*8+kt)*64 + hi*16 + l15)<<3) + j8] = f2bf(a);
  } else {
    int d=bid-768;
    for(int j=tid;j<512;j+=256) w[j]=slot_b[d*512+j]+shared_b[j];
    __syncthreads();
    int n=tid; float a=0.f;
    for(int j=0;j<512;j++) a += w[j]*star_W[j*256+n];
    ((float*)(ws+OFF_BVEC))[d*256+n]=a;
  }
}

// ============================ front kernel (sorted rows, unpadded) ============================
// 256 threads / 128 sorted rows. Block domains = contiguous [dlo,dhi] (pure for all but <=2 blocks).
__global__ __launch_bounds__(256,2) void k_front(
    const int* __restrict__ x, const float* __restrict__ emb_tables,
    u16* __restrict__ wsu)
{
  __shared__ __align__(16) u16 shbuf[33792];   // trb[4][32][264] ; aliases Wbuf[2][8192]
  __shared__ float bvecL[768];
  __shared__ float parF[1536];

  const int tid=threadIdx.x, lane=tid&63, wv=tid>>6;
  const int l15=lane&15, hq=lane>>4;
  const int b0=blockIdx.x*128, rowbase=b0+wv*32;
  const f32x4 fz={0.f,0.f,0.f,0.f};
  const s16x8 zf={0,0,0,0,0,0,0,0};
  u16* Wb[2]={shbuf, shbuf+8192};
  u16* trbw = shbuf + wv*8448;   // [32][264]
  u16* embp = wsu+OFF_EMB;
  const u32* perm=(const u32*)(wsu+OFF_PERM);

  gstage(wsu+OFF_SKIPW, Wb[0], 16384, wv, lane, 4);
  gstage(wsu+OFF_BVEC, (u16*)bvecL, 3072, wv, lane, 4);
  gstage(wsu+OFF_PARF, (u16*)parF, 6144, wv, lane, 4);

  const int dlo=__builtin_amdgcn_readfirstlane(x[15*B_TOT+(int)perm[b0]]);
  const int dhi=__builtin_amdgcn_readfirstlane(x[15*B_TOT+(int)perm[b0+127]]);

  int dmA[2], dm[2][4];
  s16x8 af[2][8];
#pragma unroll
  for(int rt=0;rt<2;rt++){
    int prow=(int)perm[rowbase+rt*16+l15];
    dmA[rt]=x[15*B_TOT+prow];
#pragma unroll
    for(int r=0;r<4;r++) dm[rt][r]=x[15*B_TOT+(int)perm[rowbase+rt*16+hq*4+r]];
#pragma unroll
    for(int kt=0;kt<8;kt++){
      int f=kt*2+(hq>>1), j0=(hq&1)*8;
      int idx=x[f*B_TOT+prow];
      const float* sp=emb_tables + (size_t)(f*1000+idx)*16 + j0;
      float4 v0=*(const float4*)sp, v1=*(const float4*)(sp+4);
      union{ u16 h[8]; s16x8 v; } t;
      t.h[0]=f2bf(v0.x); t.h[1]=f2bf(v0.y); t.h[2]=f2bf(v0.z); t.h[3]=f2bf(v0.w);
      t.h[4]=f2bf(v1.x); t.h[5]=f2bf(v1.y); t.h[6]=f2bf(v1.z); t.h[7]=f2bf(v1.w);
      af[rt][kt]=t.v;
    }
  }
  __syncthreads();
  int cur=0;

  f32x4 acc[2][16];
#pragma unroll
  for(int rt=0;rt<2;rt++)
#pragma unroll
    for(int ct=0;ct<16;ct++) acc[rt][ct]=fz;

  // ---- skip MLP: 8 chunks ----
#pragma unroll
  for(int c=0;c<8;c++){
    if(c<7) gstage(wsu+OFF_SKIPW+(c+1)*8192, Wb[cur^1], 16384, wv, lane, 4);
    const u16* B=Wb[cur];
#pragma unroll
    for(int kt=0;kt<8;kt++){
#pragma unroll
      for(int i=0;i<2;i++){
        s16x8 bf=*(const s16x8*)(B + (((i*8+kt)*64+lane)<<3));
        acc[0][c*2+i]=mfma16(af[0][kt],bf,acc[0][c*2+i]);
        acc[1][c*2+i]=mfma16(af[1][kt],bf,acc[1][c*2+i]);
      }
    }
    __syncthreads(); cur^=1;
  }
  // skip epilogue -> trb
#pragma unroll
  for(int rt=0;rt<2;rt++){
#pragma unroll
    for(int ct=0;ct<16;ct++){ float bb=parF[ct*16+l15];
#pragma unroll
      for(int r=0;r<4;r++) acc[rt][ct][r]+=bb; }
    float mu[4],rs[4];
    ln16<16>(&acc[rt][0], 1.f/256.f, mu, rs);
#pragma unroll
    for(int ct=0;ct<16;ct++){
      int col=ct*16+l15;
      float gv=parF[256+col], bev=parF[512+col];
#pragma unroll
      for(int r=0;r<4;r++){
        float v=fmaxf((acc[rt][ct][r]-mu[r])*rs[r]*gv+bev,0.f);
        trbw[(rt*16+hq*4+r)*264 + col]=f2bf(v);
      }
    }
  }
  lds_fence();
  // store skip frags to global emb (read back at the end)
#pragma unroll
  for(int rt=0;rt<2;rt++){
    int rtg=(b0>>4)+wv*2+rt;
#pragma unroll
    for(int kt=0;kt<8;kt++){
      s16x8 v=*(const s16x8*)(trbw + (rt*16+l15)*264 + kt*32+hq*8);
      *(s16x8*)(embp + (((size_t)(rtg*8+kt)*64+lane)<<3)) = v;
    }
  }
  __syncthreads();                       // all trb reads done -> Wbuf reusable
  gstage(wsu+OFF_MD+dlo*65536, Wb[0], 16384, wv, lane, 4);
  __syncthreads();
  cur=0;

  // ---- star: sum over dd in [dlo,dhi] of mask_dd(row) @ Md[dd] ----
#pragma unroll
  for(int rt=0;rt<2;rt++)
#pragma unroll
    for(int ct=0;ct<16;ct++) acc[rt][ct]=fz;
  for(int dd=dlo;dd<=dhi;dd++){
#pragma unroll
    for(int c=0;c<8;c++){
      if(c<7)        gstage(wsu+OFF_MD+dd*65536+(c+1)*8192, Wb[cur^1], 16384, wv, lane, 4);
      else if(dd<dhi) gstage(wsu+OFF_MD+(dd+1)*65536,       Wb[cur^1], 16384, wv, lane, 4);
      const u16* B=Wb[cur];
#pragma unroll
      for(int kt=0;kt<8;kt++){
        s16x8 a0=(dmA[0]==dd)?af[0][kt]:zf;    // inline mask: no 64-reg hoist
        s16x8 a1=(dmA[1]==dd)?af[1][kt]:zf;
#pragma unroll
        for(int i=0;i<2;i++){
          s16x8 bf=*(const s16x8*)(B + (((i*8+kt)*64+lane)<<3));
          acc[0][c*2+i]=mfma16(a0,bf,acc[0][c*2+i]);
          acc[1][c*2+i]=mfma16(a1,bf,acc[1][c*2+i]);
        }
      }
      __syncthreads(); cur^=1;
    }
  }

  // star epilogue -> trb -> + skip frags (global) -> final emb frags
#pragma unroll
  for(int rt=0;rt<2;rt++){
#pragma unroll
    for(int ct=0;ct<16;ct++){
      int col=ct*16+l15; float sb=parF[768+col];
#pragma unroll
      for(int r=0;r<4;r++) acc[rt][ct][r] += sb + bvecL[dm[rt][r]*256+col];
    }
    float mu[4],rs[4];
    ln16<16>(&acc[rt][0], 1.f/256.f, mu, rs);
#pragma unroll
    for(int ct=0;ct<16;ct++){
      int col=ct*16+l15;
      float gv=parF[1024+col], bev=parF[1280+col];
#pragma unroll
      for(int r=0;r<4;r++){
        float v=fmaxf((acc[rt][ct][r]-mu[r])*rs[r]*gv+bev,0.f);
        trbw[(rt*16+hq*4+r)*264 + col]=f2bf(v);
      }
    }
  }
  lds_fence();
#pragma unroll
  for(int rt=0;rt<2;rt++){
    int rtg=(b0>>4)+wv*2+rt;
#pragma unroll
    for(int kt=0;kt<8;kt++){
      s16x8 vs=*(const s16x8*)(trbw + (rt*16+l15)*264 + kt*32+hq*8);
      s16x8 vk=*(const s16x8*)(embp + (((size_t)(rtg*8+kt)*64+lane)<<3));
      union{ u16 h[8]; s16x8 v; } t;
#pragma unroll
      for(int j=0;j<8;j++) t.h[j]=f2bf(bf2f((u16)vs[j])+bf2f((u16)vk[j]));
      *(s16x8*)(embp + (((size_t)(rtg*8+kt)*64+lane)<<3)) = t.v;
    }
  }
}

// ============================ k_B: 8-wave / 256-row blocks, 32KB slots, ~37 phases ====
// Experiment: per-phase cost has been ~3.5us regardless of phase work (r1/r4/r6) ->
// halve the PHASE COUNT by doubling the slot to 32KB. 2-slot ring, vmcnt(0)+lgkmcnt(0)
// +barrier per phase (r6 proven-safe), trb pitch 136, expert LN params from global (r6).
// Phases: [0]=gates(24KB); per unit ui: W1a(32KB), W1b(32KB), W2(16KB); per domain:
// 2x dskip(32KB each); 1x towers(16KB = two 8KB k6 tables).
__device__ __forceinline__ void stage_phase8(int p, int dlo, int ndom,
    const u16* wsu, u16* slot, int wv, int lane){
  const int NU=10+ndom;
  const int PD=1+3*NU, PT=PD+2*ndom;
  if(p==0){ gstage(wsu+OFF_GATEW, slot, 24576, wv, lane, 8); return; }
  if(p<PD){ int q=p-1, ui=q/3, s=q%3;
    int u=(ui<8)?ui:(ui<8+ndom)?(8+dlo+(ui-8)):(11+(ui-8-ndom));
    if(s==0)      gstage(wsu+OFF_EXPW1+(size_t)u*32768,       slot, 32768, wv, lane, 8);
    else if(s==1) gstage(wsu+OFF_EXPW1+(size_t)u*32768+16384, slot, 32768, wv, lane, 8);
    else          gstage(wsu+OFF_EXPW2+(size_t)u*8192,        slot, 16384, wv, lane, 8);
    return; }
  if(p<PT){ int q=p-PD; int dd=dlo+(q>>1); int jj=(q&1)?(3+dd):dd;
    gstage(wsu+OFF_DSKIPW+(size_t)jj*16384, slot, 32768, wv, lane, 8); return; }
  { int t=p-PT; int dd=dlo+t;
    gstage(wsu+OFF_TOWW1+(size_t)dd*4096,     slot,      8192, wv, lane, 8);
    gstage(wsu+OFF_TOWW1+(size_t)(3+dd)*4096, slot+4096, 8192, wv, lane, 8); }
}
__device__ __forceinline__ void endph(){
  asm volatile("s_waitcnt vmcnt(0) lgkmcnt(0)\n\ts_barrier" ::: "memory");
  __builtin_amdgcn_sched_barrier(0);
}

__global__ __launch_bounds__(512,2) void k_B(
    const int* __restrict__ x, u16* __restrict__ wsu, float* __restrict__ out)
{
  __shared__ __align__(16) u16 Wb[2][16384];       // 64KB 2-slot ring (32KB slots)
  __shared__ __align__(16) u16 trb[8][32][136];    // 69.6KB per-wave transpose (16B-aligned rows)
  __shared__ __align__(16) u32 gateF[256][8];      // 8KB (g_T0|g_T1) packed bf16
  __shared__ __align__(16) u16 parT[4096];         // 8KB: par[PAR_DSK..] dskip/tower/gate

  const int tid=threadIdx.x, lane=tid&63, wv=tid>>6;
  const int l15=lane&15, hq=lane>>4;
  const int b0=blockIdx.x*256, rowbase=b0+wv*32;
  const f32x4 fz={0.f,0.f,0.f,0.f};
  const u16* embp=wsu+OFF_EMB;
  const u16* parE=wsu+OFF_PAR;       // expert LN params: direct global (L2)
  const u32* perm=(const u32*)(wsu+OFF_PERM);
  u16* trbw=&trb[wv][0][0];

  const int dlo=__builtin_amdgcn_readfirstlane(x[15*B_TOT+(int)perm[b0]]);
  const int dhi=__builtin_amdgcn_readfirstlane(x[15*B_TOT+(int)perm[b0+255]]);
  const int ndom=dhi-dlo+1;
  const int NU=10+ndom;
  const int PD=1+3*NU, PT=PD+2*ndom, P3=PT+ndom;

  stage_phase8(0, dlo, ndom, wsu, &Wb[0][0], wv, lane);   // gates 24KB
  gstage(wsu+OFF_PAR+PAR_DSK, parT, 8192, wv, lane, 8);   // 8KB par tail

  u32 pv[2][4]; int dm[2][4];
#pragma unroll
  for(int rt=0;rt<2;rt++)
#pragma unroll
    for(int r=0;r<4;r++){
      u32 pp=perm[rowbase + rt*16 + hq*4 + r];
      pv[rt][r]=pp;
      dm[rt][r]=x[15*B_TOT+(int)pp];
    }

  s16x8 af[2][8];
#pragma unroll
  for(int rt=0;rt<2;rt++){
    int rtg=(rowbase>>4)+rt;
#pragma unroll
    for(int kt=0;kt<8;kt++)
      af[rt][kt]=*(const s16x8*)(embp + (((size_t)(rtg*8+kt)*64+lane)<<3));
  }

  f32x4 fa0[2][4], fa1[2][4];   // fused accumulators, C-frag layout, T=0 / T=1
#pragma unroll
  for(int rt=0;rt<2;rt++)
#pragma unroll
    for(int ct=0;ct<4;ct++){ fa0[rt][ct]=fz; fa1[rt][ct]=fz; }

  asm volatile("s_waitcnt vmcnt(0)" ::: "memory");
  __syncthreads();              // phase-0 weights + parT visible
  int p=0;

  // ---- gates (phase 0): 3 cts x 8 kt from 24KB slot ----
  {
    stage_phase8(1, dlo, ndom, wsu, &Wb[1][0], wv, lane);
    f32x4 gacc[2][3];
#pragma unroll
    for(int rt=0;rt<2;rt++)
#pragma unroll
      for(int ct=0;ct<3;ct++) gacc[rt][ct]=fz;
#pragma unroll
    for(int kt=0;kt<8;kt++){
      s16x8 wf[3];
#pragma unroll
      for(int ct=0;ct<3;ct++) wf[ct]=*(const s16x8*)(&Wb[0][0] + (((ct*8+kt)*64+lane)<<3));
#pragma unroll
      for(int ct=0;ct<3;ct++){
        gacc[0][ct]=mfma16(af[0][kt],wf[ct],gacc[0][ct]);
        gacc[1][ct]=mfma16(af[1][kt],wf[ct],gacc[1][ct]);
      }
    }
    u16* gFh=(u16*)&gateF[0][0];
#pragma unroll
    for(int rt=0;rt<2;rt++)
#pragma unroll
      for(int ct=0;ct<3;ct++){
        int k6=ct*2+(l15>>3), e=l15&7;
        float gb=bf2f(parT[(PAR_GB-PAR_DSK) + k6*8+e]);
#pragma unroll
        for(int r=0;r<4;r++){
          float v=gacc[rt][ct][r]+gb;
          float mx=v;
          mx=fmaxf(mx,__shfl_xor(mx,1,8)); mx=fmaxf(mx,__shfl_xor(mx,2,8)); mx=fmaxf(mx,__shfl_xor(mx,4,8));
          float pe=__expf(v-mx);
          float ss=pe;
          ss+=__shfl_xor(ss,1,8); ss+=__shfl_xor(ss,2,8); ss+=__shfl_xor(ss,4,8);
          int brow=wv*32+rt*16+hq*4+r;
          int dmv=dm[rt][r];
          if(k6==dmv)   gFh[(brow*8+e)*2]  =f2bf(pe/ss);
          if(k6==3+dmv) gFh[(brow*8+e)*2+1]=f2bf(pe/ss);
        }
      }
    lds_fence();
    endph(); p=1;
  }

  // ---- NU two-layer units: exp0..7, dexp[dlo..dhi], texp0, texp1 ----
  for(int ui=0;ui<NU;ui++){
    const int u = (ui<8)? ui : (ui<8+ndom)? (8+dlo+(ui-8)) : (11+(ui-8-ndom));
    const u16* pe_=parE + u*576;
    f32x4 acc1[2][8];
#pragma unroll
    for(int rt=0;rt<2;rt++)
#pragma unroll
      for(int ct=0;ct<8;ct++) acc1[rt][ct]=fz;
    // W1a: ct 0..3
    {
      const u16* Bw=&Wb[p&1][0];
      stage_phase8(p+1, dlo, ndom, wsu, &Wb[(p+1)&1][0], wv, lane);
#pragma unroll
      for(int kt=0;kt<8;kt++){
        s16x8 wf[4];
#pragma unroll
        for(int ct=0;ct<4;ct++) wf[ct]=*(const s16x8*)(Bw + (((ct*8+kt)*64+lane)<<3));
#pragma unroll
        for(int ct=0;ct<4;ct++){
          acc1[0][ct]=mfma16(af[0][kt],wf[ct],acc1[0][ct]);
          acc1[1][ct]=mfma16(af[1][kt],wf[ct],acc1[1][ct]);
        }
      }
      endph(); p++;
    }
    // W1b: ct 4..7
    {
      const u16* Bw=&Wb[p&1][0];
      stage_phase8(p+1, dlo, ndom, wsu, &Wb[(p+1)&1][0], wv, lane);
#pragma unroll
      for(int kt=0;kt<8;kt++){
        s16x8 wf[4];
#pragma unroll
        for(int ct=0;ct<4;ct++) wf[ct]=*(const s16x8*)(Bw + (((ct*8+kt)*64+lane)<<3));
#pragma unroll
        for(int ct=0;ct<4;ct++){
          acc1[0][4+ct]=mfma16(af[0][kt],wf[ct],acc1[0][4+ct]);
          acc1[1][4+ct]=mfma16(af[1][kt],wf[ct],acc1[1][4+ct]);
        }
      }
      endph(); p++;
    }
    // W2 phase (16KB slot)
    {
      const u16* Bw=&Wb[p&1][0];
      if(p+1<P3) stage_phase8(p+1, dlo, ndom, wsu, &Wb[(p+1)&1][0], wv, lane);
      // layer-1 epilogue -> trb
#pragma unroll
      for(int rt=0;rt<2;rt++){
#pragma unroll
        for(int ct=0;ct<8;ct++){ float bb=bf2f(pe_[ct*16+l15]);
#pragma unroll
          for(int r=0;r<4;r++) acc1[rt][ct][r]+=bb; }
        float mu[4],rs[4],nm[4];
        ln16<8>(&acc1[rt][0],1.f/128.f,mu,rs);
#pragma unroll
        for(int r=0;r<4;r++) nm[r]=-mu[r]*rs[r];
#pragma unroll
        for(int ct=0;ct<8;ct++){
          int col=ct*16+l15;
          float gv=bf2f(pe_[128+col]), bev=bf2f(pe_[256+col]);
#pragma unroll
          for(int r=0;r<4;r++){
            float vn=fmaf(acc1[rt][ct][r],rs[r],nm[r]);
            trbw[(rt*16+hq*4+r)*136+col]=f2bf(fmaxf(fmaf(vn,gv,bev),0.f));
          }
        }
      }
      lds_fence();
      s16x8 af2[2][4];
#pragma unroll
      for(int rt=0;rt<2;rt++)
#pragma unroll
        for(int kt=0;kt<4;kt++)
          af2[rt][kt]=*(const s16x8*)(trbw+(rt*16+l15)*136+kt*32+hq*8);
      lds_fence();
      f32x4 acc2[2][4];
#pragma unroll
      for(int rt=0;rt<2;rt++)
#pragma unroll
        for(int ct=0;ct<4;ct++) acc2[rt][ct]=fz;
#pragma unroll
      for(int kt=0;kt<4;kt++){
        s16x8 wf[4];
#pragma unroll
        for(int ct=0;ct<4;ct++) wf[ct]=*(const s16x8*)(Bw + (((ct*4+kt)*64+lane)<<3));
#pragma unroll
        for(int ct=0;ct<4;ct++){
          acc2[0][ct]=mfma16(af2[0][kt],wf[ct],acc2[0][ct]);
          acc2[1][ct]=mfma16(af2[1][kt],wf[ct],acc2[1][ct]);
        }
      }
      // layer-2 epilogue + gated fusion (per-row weights): stays in registers
#pragma unroll
      for(int rt=0;rt<2;rt++){
#pragma unroll
        for(int ct=0;ct<4;ct++){ float bb=bf2f(pe_[384+ct*16+l15]);
#pragma unroll
          for(int r=0;r<4;r++) acc2[rt][ct][r]+=bb; }
        float mu[4],rs[4],nm[4];
        ln16<4>(&acc2[rt][0],1.f/64.f,mu,rs);
#pragma unroll
        for(int r=0;r<4;r++) nm[r]=-mu[r]*rs[r];
        float g0v[4],g1v[4];
        if(ui<8){
#pragma unroll
          for(int r=0;r<4;r++){ u32 gg=gateF[wv*32+rt*16+hq*4+r][ui];
            g0v[r]=bf2f((u16)(gg&0xffffu)); g1v[r]=bf2f((u16)(gg>>16)); }
        } else if(ui<8+ndom){
          int du=dlo+(ui-8);
#pragma unroll
          for(int r=0;r<4;r++){ float m=(dm[rt][r]==du)?1.f:0.f; g0v[r]=m; g1v[r]=m; }
        } else {
          int q=ui-8-ndom;
#pragma unroll
          for(int r=0;r<4;r++){
            g0v[r]=((dm[rt][r]&1)==q)?1.f:0.f;
            g1v[r]=(((dm[rt][r]+1)&1)==q)?1.f:0.f;
          }
        }
#pragma unroll
        for(int ct=0;ct<4;ct++){
          int col=ct*16+l15;
          float gv=bf2f(pe_[448+col]), bev=bf2f(pe_[512+col]);
#pragma unroll
          for(int r=0;r<4;r++){
            float vn=fmaf(acc2[rt][ct][r],rs[r],nm[r]);
            float o=fmaxf(fmaf(vn,gv,bev),0.f);
            fa0[rt][ct][r]=fmaf(g0v[r],o,fa0[rt][ct][r]);
            fa1[rt][ct][r]=fmaf(g1v[r],o,fa1[rt][ct][r]);
          }
        }
      }
      endph(); p++;
    }
  }

  // ---- dskip units: one 32KB phase per unit; dq even->fa0 (j=dd), odd->fa1 (j=3+dd) ----
  for(int dq=0;dq<2*ndom;dq++){
    const int dd=dlo+(dq>>1);
    const int jj=(dq&1)? (3+dd) : dd;
    const u16* Bw=&Wb[p&1][0];
    if(p+1<P3) stage_phase8(p+1, dlo, ndom, wsu, &Wb[(p+1)&1][0], wv, lane);
    f32x4 a3[2][4];
#pragma unroll
    for(int rt=0;rt<2;rt++)
#pragma unroll
      for(int ct=0;ct<4;ct++) a3[rt][ct]=fz;
#pragma unroll
    for(int kt=0;kt<8;kt++){
      s16x8 wf[4];
#pragma unroll
      for(int ct=0;ct<4;ct++) wf[ct]=*(const s16x8*)(Bw + (((ct*8+kt)*64+lane)<<3));
#pragma unroll
      for(int ct=0;ct<4;ct++){
        a3[0][ct]=mfma16(af[0][kt],wf[ct],a3[0][ct]);
        a3[1][ct]=mfma16(af[1][kt],wf[ct],a3[1][ct]);
      }
    }
    const int pb=jj*192;    // within parT
#pragma unroll
    for(int rt=0;rt<2;rt++){
#pragma unroll
      for(int ct=0;ct<4;ct++){ float bb=bf2f(parT[pb+ct*16+l15]);
#pragma unroll
        for(int r=0;r<4;r++) a3[rt][ct][r]+=bb; }
      float mu[4],rs[4],nm[4],mk[4];
      ln16<4>(&a3[rt][0],1.f/64.f,mu,rs);
#pragma unroll
      for(int r=0;r<4;r++){ nm[r]=-mu[r]*rs[r]; mk[r]=(dm[rt][r]==dd)?0.5f:0.f; }
#pragma unroll
      for(int ct=0;ct<4;ct++){
        int col=ct*16+l15;
        float gv=bf2f(parT[pb+64+col]), bev=bf2f(parT[pb+128+col]);
#pragma unroll
        for(int r=0;r<4;r++){
          float vn=fmaf(a3[rt][ct][r],rs[r],nm[r]);
          float o=fmaxf(fmaf(vn,gv,bev),0.f);
          if((dq&1)==0) fa0[rt][ct][r]=fmaf(mk[r],o,fa0[rt][ct][r]);
          else          fa1[rt][ct][r]=fmaf(mk[r],o,fa1[rt][ct][r]);
        }
      }
    }
    endph(); p++;
  }

  // ---- transpose fused accumulators to A-frags (T=0 cols 0..63, T=1 cols 64..127) ----
#pragma unroll
  for(int rt=0;rt<2;rt++)
#pragma unroll
    for(int ct=0;ct<4;ct++)
#pragma unroll
      for(int r=0;r<4;r++){
        int rr=(rt*16+hq*4+r)*136 + ct*16+l15;
        trbw[rr]   =f2bf(fa0[rt][ct][r]);
        trbw[rr+64]=f2bf(fa1[rt][ct][r]);
      }
  lds_fence();
  s16x8 aft0[2][2], aft1[2][2];
#pragma unroll
  for(int rt=0;rt<2;rt++)
#pragma unroll
    for(int kt=0;kt<2;kt++){
      aft0[rt][kt]=*(const s16x8*)(trbw+(rt*16+l15)*136+kt*32+hq*8);
      aft1[rt][kt]=*(const s16x8*)(trbw+(rt*16+l15)*136+64+kt*32+hq*8);
    }
  lds_fence();

  // ---- towers: per domain dd one 16KB phase (k6=dd at slot[0:8KB), 3+dd at [8KB:16KB)) ----
  for(int t=0;t<ndom;t++){
    const u16* Bw=&Wb[p&1][0];
    if(p+1<P3) stage_phase8(p+1, dlo, ndom, wsu, &Wb[(p+1)&1][0], wv, lane);
    const int dd=dlo+t;
#pragma unroll
    for(int s=0;s<2;s++){
      const int k6 = s? (3+dd) : dd;
      f32x4 ta[2][4];
#pragma unroll
      for(int rt=0;rt<2;rt++)
#pragma unroll
        for(int ct=0;ct<4;ct++) ta[rt][ct]=fz;
#pragma unroll
      for(int kt=0;kt<2;kt++){
        s16x8 wf[4];
#pragma unroll
        for(int ct=0;ct<4;ct++) wf[ct]=*(const s16x8*)(Bw + s*4096 + (((ct*2+kt)*64+lane)<<3));
#pragma unroll
        for(int ct=0;ct<4;ct++){
          if(s==0){ ta[0][ct]=mfma16(aft0[0][kt],wf[ct],ta[0][ct]); ta[1][ct]=mfma16(aft0[1][kt],wf[ct],ta[1][ct]); }
          else    { ta[0][ct]=mfma16(aft1[0][kt],wf[ct],ta[0][ct]); ta[1][ct]=mfma16(aft1[1][kt],wf[ct],ta[1][ct]); }
        }
      }
      const int pb=(PAR_TOW-PAR_DSK)+k6*256;   // within parT
#pragma unroll
      for(int rt=0;rt<2;rt++){
#pragma unroll
        for(int ct=0;ct<4;ct++){ float bb=bf2f(parT[pb+ct*16+l15]);
#pragma unroll
          for(int r=0;r<4;r++) ta[rt][ct][r]+=bb; }
        float mu[4],rs[4],nm[4];
        ln16<4>(&ta[rt][0],1.f/64.f,mu,rs);
#pragma unroll
        for(int r=0;r<4;r++) nm[r]=-mu[r]*rs[r];
        float pr[4]={0.f,0.f,0.f,0.f};
#pragma unroll
        for(int ct=0;ct<4;ct++){
          int col=ct*16+l15;
          float gv=bf2f(parT[pb+64+col]), bev=bf2f(parT[pb+128+col]), w2=bf2f(parT[pb+192+col]);
#pragma unroll
          for(int r=0;r<4;r++){
            float vn=fmaf(ta[rt][ct][r],rs[r],nm[r]);
            float o=fmaxf(fmaf(vn,gv,bev),0.f);
            pr[r]=fmaf(o,w2,pr[r]);
          }
        }
#pragma unroll
        for(int m=1;m<16;m<<=1){
#pragma unroll
          for(int r=0;r<4;r++) pr[r]+=__shfl_xor(pr[r],m,16);
        }
        if(l15==0){
          float tb2=bf2f(parT[(PAR_TB2-PAR_DSK)+k6]);
#pragma unroll
          for(int r=0;r<4;r++){
            if(dm[rt][r]==dd){
              float sv=pr[r]+tb2;
              out[(size_t)pv[rt][r]*2 + s] = 1.f/(1.f+__expf(-sv));
            }
          }
        }
      }
    }
    if(p+1<P3) endph();
    p++;
  }
}

// ============================ launcher ============================
extern "C" void kernel_launch(void* const* d_in, const int* in_sizes, int n_in,
                              void* d_out, int out_size, void* d_ws, size_t ws_size,
                              hipStream_t stream)
{
  if(ws_size < (size_t)(OFF_CNT+32)*2) return;

  const int*   x          =(const int*)  d_in[0];
  const float* emb_tables =(const float*)d_in[1];
  const float* skip_W     =(const float*)d_in[2];
  const float* skip_b     =(const float*)d_in[3];
  const float* skip_g     =(const float*)d_in[4];
  const float* skip_be    =(const float*)d_in[5];
  const float* shared_W   =(const float*)d_in[6];
  const float* shared_b   =(const float*)d_in[7];
  const float* slot_W     =(const float*)d_in[8];
  const float* slot_b     =(const float*)d_in[9];
  const float* star_W     =(const float*)d_in[10];
  const float* star_b     =(const float*)d_in[11];
  const float* star_g     =(const float*)d_in[12];
  const float* star_be    =(const float*)d_in[13];
  const float* dskip_W    =(const float*)d_in[14];
  const float* dskip_b    =(const float*)d_in[15];
  const float* dskip_g    =(const float*)d_in[16];
  const float* dskip_be   =(const float*)d_in[17];
  const float* exp_W1     =(const float*)d_in[18];
  const float* exp_b1     =(const float*)d_in[19];
  const float* exp_g1     =(const float*)d_in[20];
  const float* exp_be1    =(const float*)d_in[21];
  const float* exp_W2     =(const float*)d_in[22];
  const float* exp_b2     =(const float*)d_in[23];
  const float* exp_g2     =(const float*)d_in[24];
  const float* exp_be2    =(const float*)d_in[25];
  const float* dexp_W1    =(const float*)d_in[26];
  const float* dexp_b1    =(const float*)d_in[27];
  const float* dexp_g1    =(const float*)d_in[28];
  const float* dexp_be1   =(const float*)d_in[29];
  const float* dexp_W2    =(const float*)d_in[30];
  const float* dexp_b2    =(const float*)d_in[31];
  const float* dexp_g2    =(const float*)d_in[32];
  const float* dexp_be2   =(const float*)d_in[33];
  const float* texp_W1    =(const float*)d_in[34];
  const float* texp_b1    =(const float*)d_in[35];
  const float* texp_g1    =(const float*)d_in[36];
  const float* texp_be1   =(const float*)d_in[37];
  const float* texp_W2    =(const float*)d_in[38];
  const float* texp_b2    =(const float*)d_in[39];
  const float* texp_g2    =(const float*)d_in[40];
  const float* texp_be2   =(const float*)d_in[41];
  const float* gate_W     =(const float*)d_in[42];
  const float* gate_b     =(const float*)d_in[43];
  const float* tow_W1     =(const float*)d_in[44];
  const float* tow_b1     =(const float*)d_in[45];
  const float* tow_g      =(const float*)d_in[46];
  const float* tow_be     =(const float*)d_in[47];
  const float* tow_W2     =(const float*)d_in[48];
  const float* tow_b2     =(const float*)d_in[49];

  u16* wsu=(u16*)d_ws;
  float* out=(float*)d_out;

  k_sortinit<<<1,64,0,stream>>>(wsu);
  k_count<<<B_TOT/256,256,0,stream>>>(x,wsu);
  k_scatter<<<B_TOT/256,256,0,stream>>>(x,wsu);
  k_pack<<<(OFF_BVEC+255)/256,256,0,stream>>>(skip_W,gate_W,
      exp_W1,dexp_W1,texp_W1,exp_W2,dexp_W2,texp_W2,dskip_W,tow_W1,wsu);
  k_packpar<<<46,256,0,stream>>>(
      exp_b1,exp_g1,exp_be1,exp_b2,exp_g2,exp_be2,
      dexp_b1,dexp_g1,dexp_be1,dexp_b2,dexp_g2,dexp_be2,
      texp_b1,texp_g1,texp_be1,texp_b2,texp_g2,texp_be2,
      dskip_b,dskip_g,dskip_be,gate_b,
      tow_b1,tow_g,tow_be,tow_W2,tow_b2,
      skip_b,skip_g,skip_be,star_b,star_g,star_be,wsu);
  k_fold<<<771,256,0,stream>>>(slot_W,shared_W,star_W,slot_b,shared_b,wsu);
  k_front<<<B_TOT/128,256,0,stream>>>(x,emb_tables,wsu);
  k_B<<<B_TOT/256,512,0,stream>>>(x,wsu,out);
}